// Round 8
// baseline (174.975 us; speedup 1.0000x reference)
//
#include <hip/hip_runtime.h>
#include <hip/hip_bf16.h>
#include <math.h>

typedef float floatx16 __attribute__((ext_vector_type(16)));
typedef __bf16 bf16x8 __attribute__((ext_vector_type(8)));

#define SEQ 2048
#define NH 8
#define DH 64
#define NB 2
#define HEADS 16
#define HSTRIDE (SEQ * DH)       // per-head elems in packed tensors (131072)
#define TILE_E (64 * 64)         // elems per 64-key tile

__device__ __forceinline__ unsigned short f2bf(float x) {
  union { __bf16 b; unsigned short u; } c; c.b = (__bf16)x; return c.u;
}
__device__ __forceinline__ unsigned int pk2bf(float a, float b) {
  union { __hip_bfloat162 h2; unsigned int u; } c;
  c.h2 = __float22bfloat162_rn(make_float2(a, b));
  return c.u;
}

// v_permlane32_swap_b32, orientation probed at runtime (R12-verified).
__device__ __forceinline__ void hswap_fwd(unsigned& a, unsigned& b) {
  asm volatile("v_permlane32_swap_b32 %0, %1" : "+v"(a), "+v"(b));
}
__device__ __forceinline__ void hswap_rev(unsigned& a, unsigned& b) {
  asm volatile("v_permlane32_swap_b32 %0, %1" : "+v"(b), "+v"(a));
}

// ---- pre-pass: K,V fp32 [n,s,h,d] -> bf16 in 32x32x16-MFMA fragment order ----
__global__ __launch_bounds__(256)
void pack_kv(const float* __restrict__ k, const float* __restrict__ v,
             unsigned short* __restrict__ kb, unsigned short* __restrict__ vb) {
  __shared__ unsigned short Ts[64][68];   // V tile [s][d]
  const int tid  = threadIdx.x;
  const int bx   = blockIdx.x;
  const int head = bx & 15;
  const int kt   = bx >> 4;
  const int n = head >> 3, h = head & 7;

  #pragma unroll
  for (int j2 = 0; j2 < 2; ++j2) {
    int c = j2 * 256 + tid;
    int lane = c & 63;
    int kk = (c >> 6) & 3, ks2 = c >> 8;
    int row = kt * 64 + ks2 * 32 + (lane & 31);
    int d0  = kk * 16 + (lane >> 5) * 8;
    const float* src = k + ((size_t)(n * SEQ + row) * NH + h) * DH + d0;
    float4 a = *(const float4*)src;
    float4 b = *(const float4*)(src + 4);
    ushort4 lo, hi;
    lo.x = f2bf(a.x); lo.y = f2bf(a.y); lo.z = f2bf(a.z); lo.w = f2bf(a.w);
    hi.x = f2bf(b.x); hi.y = f2bf(b.y); hi.z = f2bf(b.z); hi.w = f2bf(b.w);
    unsigned short* dst = kb + (size_t)head * HSTRIDE + kt * TILE_E + c * 8;
    *(ushort4*)dst = lo;
    *(ushort4*)(dst + 4) = hi;
  }

  #pragma unroll
  for (int i = 0; i < 4; ++i) {
    int id = i * 256 + tid;
    int s  = id >> 4;
    int c4 = (id & 15) * 4;
    size_t g = ((size_t)((n * SEQ + kt * 64 + s) * NH + h)) * DH + c4;
    float4 x = *(const float4*)(v + g);
    ushort4 y;
    y.x = f2bf(x.x); y.y = f2bf(x.y); y.z = f2bf(x.z); y.w = f2bf(x.w);
    *(ushort4*)&Ts[s][c4] = y;
  }
  __syncthreads();
  #pragma unroll
  for (int j2 = 0; j2 < 2; ++j2) {
    int c = j2 * 256 + tid;
    int lane = c & 63;
    int dsub = (c >> 6) & 1, ss = c >> 7;
    int s0 = ss * 16 + (lane >> 5) * 8;
    int d  = dsub * 32 + (lane & 31);
    ushort4 lo, hi;
    lo.x = Ts[s0 + 0][d]; lo.y = Ts[s0 + 1][d]; lo.z = Ts[s0 + 2][d]; lo.w = Ts[s0 + 3][d];
    hi.x = Ts[s0 + 4][d]; hi.y = Ts[s0 + 5][d]; hi.z = Ts[s0 + 6][d]; hi.w = Ts[s0 + 7][d];
    unsigned short* dst = vb + (size_t)head * HSTRIDE + kt * TILE_E + c * 8;
    *(ushort4*)dst = lo;
    *(ushort4*)(dst + 4) = hi;
  }
}

// ---- attention (R8): R7 dual-chain at 3 waves/SIMD + cross-iteration kA0
//      double-buffer. Dependence audit of R7: vb0/kA1/vb1 all have 200-400cy
//      of cover, but kA0 is issued at iter top and consumed IMMEDIATELY by
//      QK0 — one exposed ~250cy L2 round-trip per iter per wave. Fix: named
//      kE/kO buffers alternated by an explicit 2-body loop (static indexing
//      regardless of unroller); kA0(it+1) prefetch issued right after QK1
//      (cover = PV0+exp1+PV1+iter-top ~400cy). Peak live ~150 regs < 168
//      budget of (256,3). Tripwire: attn WRITE_SIZE must stay ~8MB.
#define SMEM_BYTES (4 * 16 * 72 * 4 + 4 * 16 * 4)   // oM 18432 + lM 256

__global__ __launch_bounds__(256, 3)
void attn(const float* __restrict__ q, const unsigned short* __restrict__ kb,
          const unsigned short* __restrict__ vt, float* __restrict__ out) {
  __shared__ __align__(16) char smem[SMEM_BYTES];
  float* oM = (float*)smem;                             // [4][16][72]
  float* lM = (float*)(smem + 4 * 16 * 72 * 4);         // [4][16]

  const int tid  = threadIdx.x;
  const int wave = tid >> 6;
  const int lane = tid & 63;
  const int l32  = lane & 31;
  const int hl   = lane >> 5;

  // probe permlane32_swap orientation (wave-uniform)
  unsigned px = (unsigned)lane, py = (unsigned)lane + 100u;
  hswap_fwd(px, py);
  const bool mir = (__builtin_amdgcn_readfirstlane(px) != 0u);

  const int bx   = blockIdx.x;
  const int head = bx & 15;          // XCD h%8 affinity — matches pack's writes
  const int qc   = bx >> 4;          // 0..63, 32 q-rows per block
  const int n = head >> 3, h = head & 7;

  const int swk = __builtin_amdgcn_readfirstlane(wave);   // key-quarter, SGPR
  const unsigned short* kq = kb + (size_t)head * HSTRIDE + (size_t)swk * 8 * TILE_E;
  const unsigned short* vq = vt + (size_t)head * HSTRIDE + (size_t)swk * 8 * TILE_E;

  const float S = 0.125f * 1.4426950408889634f;   // folded into Q at init

  // Q B-fragments (pre-scaled by S): lane holds Q[q = qc*32 + l32][d = kk*16 + hl*8 + j]
  bf16x8 qB[4];
  #pragma unroll
  for (int kk = 0; kk < 4; ++kk) {
    const int row = qc * 32 + l32;
    const float* src = q + ((size_t)((n * SEQ + row) * NH + h)) * DH + kk * 16 + hl * 8;
    float4 x0 = *(const float4*)src;
    float4 x1 = *(const float4*)(src + 4);
    union { unsigned int u32[4]; bf16x8 v8; } u;
    u.u32[0] = pk2bf(x0.x * S, x0.y * S); u.u32[1] = pk2bf(x0.z * S, x0.w * S);
    u.u32[2] = pk2bf(x1.x * S, x1.y * S); u.u32[3] = pk2bf(x1.z * S, x1.w * S);
    qB[kk] = u.v8;
  }

  floatx16 o[2];
  float lsum = 0.f;
  #pragma unroll
  for (int d = 0; d < 2; ++d)
    #pragma unroll
    for (int i = 0; i < 16; ++i) o[d][i] = 0.f;

  // one 64-key tile. kC = this tile's kA0 (already resident); kN gets the
  // NEXT tile's kA0 (prefetch issued after QK1 when pf).
  auto body = [&](int it, bf16x8 (&kC)[4], bf16x8 (&kN)[4], bool pf) {
    const unsigned short* tb_k = kq + it * TILE_E;
    const unsigned short* tb_v = vq + it * TILE_E;

    bf16x8 kA1[4];
    bf16x8 vb0[2][2], vb1[2][2];
    #pragma unroll
    for (int j = 0; j < 2; ++j)
      #pragma unroll
      for (int d = 0; d < 2; ++d)
        vb0[j][d] = *(const bf16x8*)(tb_v + ((j * 2 + d) * 64 + lane) * 8);
    #pragma unroll
    for (int kk = 0; kk < 4; ++kk)
      kA1[kk] = *(const bf16x8*)(tb_k + ((4 + kk) * 64 + lane) * 8);

    // ---- chain 0: QK over keys [it*64, it*64+32) — kC resident, NO stall ----
    floatx16 acc0;
    #pragma unroll
    for (int i = 0; i < 16; ++i) acc0[i] = 0.f;
    __builtin_amdgcn_s_setprio(1);
    #pragma unroll
    for (int kk = 0; kk < 4; ++kk)
      acc0 = __builtin_amdgcn_mfma_f32_32x32x16_bf16(kC[kk], qB[kk], acc0, 0, 0, 0);
    __builtin_amdgcn_s_setprio(0);

    // exp0 (no fma stage: S pre-folded, shift dropped — cancels in o/lsum)
    unsigned pkv0[8];
    #pragma unroll
    for (int g2 = 0; g2 < 4; ++g2) {
      float p0 = __builtin_amdgcn_exp2f(acc0[4 * g2 + 0]);
      float p1 = __builtin_amdgcn_exp2f(acc0[4 * g2 + 1]);
      float p2 = __builtin_amdgcn_exp2f(acc0[4 * g2 + 2]);
      float p3 = __builtin_amdgcn_exp2f(acc0[4 * g2 + 3]);
      lsum += (p0 + p1) + (p2 + p3);
      pkv0[g2 * 2]     = pk2bf(p0, p1);
      pkv0[g2 * 2 + 1] = pk2bf(p2, p3);
    }

    // ---- chain 1: QK over keys [it*64+32, it*64+64) — overlaps exp0 retire ----
    floatx16 acc1;
    #pragma unroll
    for (int i = 0; i < 16; ++i) acc1[i] = 0.f;
    __builtin_amdgcn_s_setprio(1);
    #pragma unroll
    for (int kk = 0; kk < 4; ++kk)
      acc1 = __builtin_amdgcn_mfma_f32_32x32x16_bf16(kA1[kk], qB[kk], acc1, 0, 0, 0);
    __builtin_amdgcn_s_setprio(0);

    // prefetch NEXT tile's kA0 (kC now dead; ~400cy cover to next QK0)
    if (pf) {
      #pragma unroll
      for (int kk = 0; kk < 4; ++kk)
        kN[kk] = *(const bf16x8*)(tb_k + TILE_E + (kk * 64 + lane) * 8);
    }

    // vb1 loads (kA1 now dead): ~300cy cover before PV1
    #pragma unroll
    for (int j = 0; j < 2; ++j)
      #pragma unroll
      for (int d = 0; d < 2; ++d)
        vb1[j][d] = *(const bf16x8*)(tb_v + (((2 + j) * 2 + d) * 64 + lane) * 8);

    // swizzle0 + PV0
    {
      union { unsigned u32[4]; bf16x8 v8; } A1, A2;
      A1.u32[0] = pkv0[0]; A1.u32[2] = pkv0[2];
      A1.u32[1] = pkv0[1]; A1.u32[3] = pkv0[3];
      A2.u32[0] = pkv0[4]; A2.u32[2] = pkv0[6];
      A2.u32[1] = pkv0[5]; A2.u32[3] = pkv0[7];
      if (!mir) {
        hswap_fwd(A1.u32[0], A1.u32[2]); hswap_fwd(A1.u32[1], A1.u32[3]);
        hswap_fwd(A2.u32[0], A2.u32[2]); hswap_fwd(A2.u32[1], A2.u32[3]);
      } else {
        hswap_rev(A1.u32[0], A1.u32[2]); hswap_rev(A1.u32[1], A1.u32[3]);
        hswap_rev(A2.u32[0], A2.u32[2]); hswap_rev(A2.u32[1], A2.u32[3]);
      }
      __builtin_amdgcn_s_setprio(1);
      o[0] = __builtin_amdgcn_mfma_f32_32x32x16_bf16(A1.v8, vb0[0][0], o[0], 0, 0, 0);
      o[1] = __builtin_amdgcn_mfma_f32_32x32x16_bf16(A1.v8, vb0[0][1], o[1], 0, 0, 0);
      o[0] = __builtin_amdgcn_mfma_f32_32x32x16_bf16(A2.v8, vb0[1][0], o[0], 0, 0, 0);
      o[1] = __builtin_amdgcn_mfma_f32_32x32x16_bf16(A2.v8, vb0[1][1], o[1], 0, 0, 0);
      __builtin_amdgcn_s_setprio(0);
    }

    // exp1 + swizzle1 + PV1
    {
      unsigned pkv1[8];
      #pragma unroll
      for (int g2 = 0; g2 < 4; ++g2) {
        float p0 = __builtin_amdgcn_exp2f(acc1[4 * g2 + 0]);
        float p1 = __builtin_amdgcn_exp2f(acc1[4 * g2 + 1]);
        float p2 = __builtin_amdgcn_exp2f(acc1[4 * g2 + 2]);
        float p3 = __builtin_amdgcn_exp2f(acc1[4 * g2 + 3]);
        lsum += (p0 + p1) + (p2 + p3);
        pkv1[g2 * 2]     = pk2bf(p0, p1);
        pkv1[g2 * 2 + 1] = pk2bf(p2, p3);
      }
      union { unsigned u32[4]; bf16x8 v8; } A1, A2;
      A1.u32[0] = pkv1[0]; A1.u32[2] = pkv1[2];
      A1.u32[1] = pkv1[1]; A1.u32[3] = pkv1[3];
      A2.u32[0] = pkv1[4]; A2.u32[2] = pkv1[6];
      A2.u32[1] = pkv1[5]; A2.u32[3] = pkv1[7];
      if (!mir) {
        hswap_fwd(A1.u32[0], A1.u32[2]); hswap_fwd(A1.u32[1], A1.u32[3]);
        hswap_fwd(A2.u32[0], A2.u32[2]); hswap_fwd(A2.u32[1], A2.u32[3]);
      } else {
        hswap_rev(A1.u32[0], A1.u32[2]); hswap_rev(A1.u32[1], A1.u32[3]);
        hswap_rev(A2.u32[0], A2.u32[2]); hswap_rev(A2.u32[1], A2.u32[3]);
      }
      __builtin_amdgcn_s_setprio(1);
      o[0] = __builtin_amdgcn_mfma_f32_32x32x16_bf16(A1.v8, vb1[0][0], o[0], 0, 0, 0);
      o[1] = __builtin_amdgcn_mfma_f32_32x32x16_bf16(A1.v8, vb1[0][1], o[1], 0, 0, 0);
      o[0] = __builtin_amdgcn_mfma_f32_32x32x16_bf16(A2.v8, vb1[1][0], o[0], 0, 0, 0);
      o[1] = __builtin_amdgcn_mfma_f32_32x32x16_bf16(A2.v8, vb1[1][1], o[1], 0, 0, 0);
      __builtin_amdgcn_s_setprio(0);
    }
  };

  // ---- pipelined loop: named kE/kO alternate as current/next kA0 ----
  bf16x8 kE[4], kO[4];
  #pragma unroll
  for (int kk = 0; kk < 4; ++kk)
    kE[kk] = *(const bf16x8*)(kq + (kk * 64 + lane) * 8);
  #pragma unroll
  for (int i2 = 0; i2 < 4; ++i2) {
    body(2 * i2,     kE, kO, true);
    body(2 * i2 + 1, kO, kE, i2 < 3);
  }

  // lanes L and L+32 hold disjoint key subsets of the same q-row
  lsum += __shfl_xor(lsum, 32, 64);

  // ---- 2-phase merge: sum the 4 key-quarter waves ----
  const int prow = tid >> 4;          // 0..15 row within phase
  const int col4 = tid & 15;          // float4 column
  #pragma unroll
  for (int p = 0; p < 2; ++p) {
    const int rh = p;
    __syncthreads();
    #pragma unroll
    for (int r8 = 0; r8 < 8; ++r8) {
      const int r   = rh * 8 + r8;
      const int rip = (r8 & 3) + 4 * hl + 8 * (r8 >> 2);   // row in phase, 0..15
      oM[(wave * 16 + rip) * 72 + l32]      = o[0][r];
      oM[(wave * 16 + rip) * 72 + 32 + l32] = o[1][r];
    }
    if (lane < 32 && ((lane >> 4) & 1) == rh) lM[wave * 16 + (lane & 15)] = lsum;
    __syncthreads();
    float4 s = make_float4(0.f, 0.f, 0.f, 0.f);
    float l = 0.f;
    #pragma unroll
    for (int w = 0; w < 4; ++w) {
      float4 t4 = *(const float4*)&oM[(w * 16 + prow) * 72 + col4 * 4];
      s.x += t4.x; s.y += t4.y; s.z += t4.z; s.w += t4.w;
      l += lM[w * 16 + prow];
    }
    float inv = 1.f / l;
    const int grow = qc * 32 + p * 16 + prow;
    float4 st; st.x = s.x * inv; st.y = s.y * inv; st.z = s.z * inv; st.w = s.w * inv;
    *(float4*)(out + ((size_t)((n * SEQ + grow) * NH + h)) * DH + col4 * 4) = st;
  }
}

extern "C" void kernel_launch(void* const* d_in, const int* in_sizes, int n_in,
                              void* d_out, int out_size, void* d_ws, size_t ws_size,
                              hipStream_t stream) {
  const float* q = (const float*)d_in[0];
  const float* k = (const float*)d_in[1];
  const float* v = (const float*)d_in[2];
  float* out = (float*)d_out;
  (void)in_sizes; (void)n_in; (void)out_size; (void)ws_size;

  unsigned short* kb = (unsigned short*)d_ws;                       // 4 MB
  unsigned short* vb = kb + (size_t)HEADS * HSTRIDE;                // 4 MB

  pack_kv<<<HEADS * (SEQ / 64), 256, 0, stream>>>(k, v, kb, vb);
  attn<<<HEADS * (SEQ / 32), 256, 0, stream>>>(q, kb, vb, out);
}

// Round 9
// 99.432 us; speedup vs baseline: 1.7598x; 1.7598x over previous
//
#include <hip/hip_runtime.h>
#include <hip/hip_bf16.h>
#include <math.h>

typedef float floatx16 __attribute__((ext_vector_type(16)));
typedef __bf16 bf16x8 __attribute__((ext_vector_type(8)));

#define SEQ 2048
#define NH 8
#define DH 64
#define NB 2
#define HEADS 16
#define HSTRIDE (SEQ * DH)       // per-head elems in packed tensors (131072)
#define TILE_E (64 * 64)         // elems per 64-key tile

__device__ __forceinline__ unsigned short f2bf(float x) {
  union { __bf16 b; unsigned short u; } c; c.b = (__bf16)x; return c.u;
}
__device__ __forceinline__ unsigned int pk2bf(float a, float b) {
  union { __hip_bfloat162 h2; unsigned int u; } c;
  c.h2 = __float22bfloat162_rn(make_float2(a, b));
  return c.u;
}

// v_permlane32_swap_b32, orientation probed at runtime (R12-verified).
__device__ __forceinline__ void hswap_fwd(unsigned& a, unsigned& b) {
  asm volatile("v_permlane32_swap_b32 %0, %1" : "+v"(a), "+v"(b));
}
__device__ __forceinline__ void hswap_rev(unsigned& a, unsigned& b) {
  asm volatile("v_permlane32_swap_b32 %0, %1" : "+v"(b), "+v"(a));
}

// ---- pre-pass: K,V fp32 [n,s,h,d] -> bf16 in 32x32x16-MFMA fragment order ----
__global__ __launch_bounds__(256)
void pack_kv(const float* __restrict__ k, const float* __restrict__ v,
             unsigned short* __restrict__ kb, unsigned short* __restrict__ vb) {
  __shared__ unsigned short Ts[64][68];   // V tile [s][d]
  const int tid  = threadIdx.x;
  const int bx   = blockIdx.x;
  const int head = bx & 15;
  const int kt   = bx >> 4;
  const int n = head >> 3, h = head & 7;

  #pragma unroll
  for (int j2 = 0; j2 < 2; ++j2) {
    int c = j2 * 256 + tid;
    int lane = c & 63;
    int kk = (c >> 6) & 3, ks2 = c >> 8;
    int row = kt * 64 + ks2 * 32 + (lane & 31);
    int d0  = kk * 16 + (lane >> 5) * 8;
    const float* src = k + ((size_t)(n * SEQ + row) * NH + h) * DH + d0;
    float4 a = *(const float4*)src;
    float4 b = *(const float4*)(src + 4);
    ushort4 lo, hi;
    lo.x = f2bf(a.x); lo.y = f2bf(a.y); lo.z = f2bf(a.z); lo.w = f2bf(a.w);
    hi.x = f2bf(b.x); hi.y = f2bf(b.y); hi.z = f2bf(b.z); hi.w = f2bf(b.w);
    unsigned short* dst = kb + (size_t)head * HSTRIDE + kt * TILE_E + c * 8;
    *(ushort4*)dst = lo;
    *(ushort4*)(dst + 4) = hi;
  }

  #pragma unroll
  for (int i = 0; i < 4; ++i) {
    int id = i * 256 + tid;
    int s  = id >> 4;
    int c4 = (id & 15) * 4;
    size_t g = ((size_t)((n * SEQ + kt * 64 + s) * NH + h)) * DH + c4;
    float4 x = *(const float4*)(v + g);
    ushort4 y;
    y.x = f2bf(x.x); y.y = f2bf(x.y); y.z = f2bf(x.z); y.w = f2bf(x.w);
    *(ushort4*)&Ts[s][c4] = y;
  }
  __syncthreads();
  #pragma unroll
  for (int j2 = 0; j2 < 2; ++j2) {
    int c = j2 * 256 + tid;
    int lane = c & 63;
    int dsub = (c >> 6) & 1, ss = c >> 7;
    int s0 = ss * 16 + (lane >> 5) * 8;
    int d  = dsub * 32 + (lane & 31);
    ushort4 lo, hi;
    lo.x = Ts[s0 + 0][d]; lo.y = Ts[s0 + 1][d]; lo.z = Ts[s0 + 2][d]; lo.w = Ts[s0 + 3][d];
    hi.x = Ts[s0 + 4][d]; hi.y = Ts[s0 + 5][d]; hi.z = Ts[s0 + 6][d]; hi.w = Ts[s0 + 7][d];
    unsigned short* dst = vb + (size_t)head * HSTRIDE + kt * TILE_E + c * 8;
    *(ushort4*)dst = lo;
    *(ushort4*)(dst + 4) = hi;
  }
}

// ---- attention (R9): R7 dual-chain + IN-PLACE rotate reloads.
//      R8 post-mortem: a second K buffer (+16 permanent regs) spilled —
//      (256,3)'s 168-reg budget has ~15 regs slack over R7's ~150 live set.
//      Zero-extra-register alternative: reload the SAME kA0 registers with
//      tile it+1 immediately after QK0 (their last read); cover = rest of
//      iteration (~600cy). Same for kA1 after QK1 (~400cy cover). Only a
//      brief SSA overlap while the QK chain retires. vb0 stays at iter top
//      (cover = QK0+exp0+QK1), vb1 mid-iter as R7. Branchless last iter:
//      uniform clamped next-tile pointer (redundant reload of tile 7).
//      Tripwire: attn WRITE_SIZE ~18MB, else spilled -> revert to R7.
#define SMEM_BYTES (4 * 16 * 72 * 4 + 4 * 16 * 4)   // oM 18432 + lM 256

__global__ __launch_bounds__(256, 3)
void attn(const float* __restrict__ q, const unsigned short* __restrict__ kb,
          const unsigned short* __restrict__ vt, float* __restrict__ out) {
  __shared__ __align__(16) char smem[SMEM_BYTES];
  float* oM = (float*)smem;                             // [4][16][72]
  float* lM = (float*)(smem + 4 * 16 * 72 * 4);         // [4][16]

  const int tid  = threadIdx.x;
  const int wave = tid >> 6;
  const int lane = tid & 63;
  const int l32  = lane & 31;
  const int hl   = lane >> 5;

  // probe permlane32_swap orientation (wave-uniform)
  unsigned px = (unsigned)lane, py = (unsigned)lane + 100u;
  hswap_fwd(px, py);
  const bool mir = (__builtin_amdgcn_readfirstlane(px) != 0u);

  const int bx   = blockIdx.x;
  const int head = bx & 15;          // XCD h%8 affinity — matches pack's writes
  const int qc   = bx >> 4;          // 0..63, 32 q-rows per block
  const int n = head >> 3, h = head & 7;

  const int swk = __builtin_amdgcn_readfirstlane(wave);   // key-quarter, SGPR
  const unsigned short* kq = kb + (size_t)head * HSTRIDE + (size_t)swk * 8 * TILE_E;
  const unsigned short* vq = vt + (size_t)head * HSTRIDE + (size_t)swk * 8 * TILE_E;

  const float S = 0.125f * 1.4426950408889634f;   // folded into Q at init

  // Q B-fragments (pre-scaled by S): lane holds Q[q = qc*32 + l32][d = kk*16 + hl*8 + j]
  bf16x8 qB[4];
  #pragma unroll
  for (int kk = 0; kk < 4; ++kk) {
    const int row = qc * 32 + l32;
    const float* src = q + ((size_t)((n * SEQ + row) * NH + h)) * DH + kk * 16 + hl * 8;
    float4 x0 = *(const float4*)src;
    float4 x1 = *(const float4*)(src + 4);
    union { unsigned int u32[4]; bf16x8 v8; } u;
    u.u32[0] = pk2bf(x0.x * S, x0.y * S); u.u32[1] = pk2bf(x0.z * S, x0.w * S);
    u.u32[2] = pk2bf(x1.x * S, x1.y * S); u.u32[3] = pk2bf(x1.z * S, x1.w * S);
    qB[kk] = u.v8;
  }

  floatx16 o[2];
  float lsum = 0.f;
  #pragma unroll
  for (int d = 0; d < 2; ++d)
    #pragma unroll
    for (int i = 0; i < 16; ++i) o[d][i] = 0.f;

  // rotating single buffers (statically indexed, reused every iteration)
  bf16x8 kA0[4], kA1[4];
  bf16x8 vb0[2][2], vb1[2][2];

  // prologue: tile 0's kA0 (QK0 consumes immediately at iter 0 top)
  #pragma unroll
  for (int kk = 0; kk < 4; ++kk)
    kA0[kk] = *(const bf16x8*)(kq + (kk * 64 + lane) * 8);

  for (int it = 0; it < 8; ++it) {
    const unsigned short* tb_k = kq + it * TILE_E;
    const unsigned short* tb_v = vq + it * TILE_E;
    // clamped next-tile base (uniform; last iter redundantly reloads tile 7)
    const unsigned short* nb_k = kq + (it < 7 ? it + 1 : 7) * TILE_E;

    // iter-top loads: vb0 (PV0 mid-iter), kA1 (QK1 after exp0)
    #pragma unroll
    for (int j = 0; j < 2; ++j)
      #pragma unroll
      for (int d = 0; d < 2; ++d)
        vb0[j][d] = *(const bf16x8*)(tb_v + ((j * 2 + d) * 64 + lane) * 8);
    #pragma unroll
    for (int kk = 0; kk < 4; ++kk)
      kA1[kk] = *(const bf16x8*)(tb_k + ((4 + kk) * 64 + lane) * 8);

    // ---- chain 0: QK over keys [it*64, it*64+32) — kA0 resident ----
    floatx16 acc0;
    #pragma unroll
    for (int i = 0; i < 16; ++i) acc0[i] = 0.f;
    __builtin_amdgcn_s_setprio(1);
    #pragma unroll
    for (int kk = 0; kk < 4; ++kk)
      acc0 = __builtin_amdgcn_mfma_f32_32x32x16_bf16(kA0[kk], qB[kk], acc0, 0, 0, 0);
    __builtin_amdgcn_s_setprio(0);

    // rotate: reload kA0 with NEXT tile (last read was QK0 above; ~600cy cover)
    #pragma unroll
    for (int kk = 0; kk < 4; ++kk)
      kA0[kk] = *(const bf16x8*)(nb_k + (kk * 64 + lane) * 8);

    // exp0 (no fma stage: S pre-folded, shift dropped — cancels in o/lsum)
    unsigned pkv0[8];
    #pragma unroll
    for (int g2 = 0; g2 < 4; ++g2) {
      float p0 = __builtin_amdgcn_exp2f(acc0[4 * g2 + 0]);
      float p1 = __builtin_amdgcn_exp2f(acc0[4 * g2 + 1]);
      float p2 = __builtin_amdgcn_exp2f(acc0[4 * g2 + 2]);
      float p3 = __builtin_amdgcn_exp2f(acc0[4 * g2 + 3]);
      lsum += (p0 + p1) + (p2 + p3);
      pkv0[g2 * 2]     = pk2bf(p0, p1);
      pkv0[g2 * 2 + 1] = pk2bf(p2, p3);
    }

    // ---- chain 1: QK over keys [it*64+32, it*64+64) — overlaps exp0 retire ----
    floatx16 acc1;
    #pragma unroll
    for (int i = 0; i < 16; ++i) acc1[i] = 0.f;
    __builtin_amdgcn_s_setprio(1);
    #pragma unroll
    for (int kk = 0; kk < 4; ++kk)
      acc1 = __builtin_amdgcn_mfma_f32_32x32x16_bf16(kA1[kk], qB[kk], acc1, 0, 0, 0);
    __builtin_amdgcn_s_setprio(0);

    // rotate: reload kA1 with NEXT tile (~400cy cover to next QK1)
    #pragma unroll
    for (int kk = 0; kk < 4; ++kk)
      kA1[kk] = *(const bf16x8*)(nb_k + ((4 + kk) * 64 + lane) * 8);

    // vb1 loads (cover = PV0 + exp1 + swizzle1 before PV1)
    #pragma unroll
    for (int j = 0; j < 2; ++j)
      #pragma unroll
      for (int d = 0; d < 2; ++d)
        vb1[j][d] = *(const bf16x8*)(tb_v + (((2 + j) * 2 + d) * 64 + lane) * 8);

    // swizzle0 + PV0
    {
      union { unsigned u32[4]; bf16x8 v8; } A1, A2;
      A1.u32[0] = pkv0[0]; A1.u32[2] = pkv0[2];
      A1.u32[1] = pkv0[1]; A1.u32[3] = pkv0[3];
      A2.u32[0] = pkv0[4]; A2.u32[2] = pkv0[6];
      A2.u32[1] = pkv0[5]; A2.u32[3] = pkv0[7];
      if (!mir) {
        hswap_fwd(A1.u32[0], A1.u32[2]); hswap_fwd(A1.u32[1], A1.u32[3]);
        hswap_fwd(A2.u32[0], A2.u32[2]); hswap_fwd(A2.u32[1], A2.u32[3]);
      } else {
        hswap_rev(A1.u32[0], A1.u32[2]); hswap_rev(A1.u32[1], A1.u32[3]);
        hswap_rev(A2.u32[0], A2.u32[2]); hswap_rev(A2.u32[1], A2.u32[3]);
      }
      __builtin_amdgcn_s_setprio(1);
      o[0] = __builtin_amdgcn_mfma_f32_32x32x16_bf16(A1.v8, vb0[0][0], o[0], 0, 0, 0);
      o[1] = __builtin_amdgcn_mfma_f32_32x32x16_bf16(A1.v8, vb0[0][1], o[1], 0, 0, 0);
      o[0] = __builtin_amdgcn_mfma_f32_32x32x16_bf16(A2.v8, vb0[1][0], o[0], 0, 0, 0);
      o[1] = __builtin_amdgcn_mfma_f32_32x32x16_bf16(A2.v8, vb0[1][1], o[1], 0, 0, 0);
      __builtin_amdgcn_s_setprio(0);
    }

    // exp1 + swizzle1 + PV1
    {
      unsigned pkv1[8];
      #pragma unroll
      for (int g2 = 0; g2 < 4; ++g2) {
        float p0 = __builtin_amdgcn_exp2f(acc1[4 * g2 + 0]);
        float p1 = __builtin_amdgcn_exp2f(acc1[4 * g2 + 1]);
        float p2 = __builtin_amdgcn_exp2f(acc1[4 * g2 + 2]);
        float p3 = __builtin_amdgcn_exp2f(acc1[4 * g2 + 3]);
        lsum += (p0 + p1) + (p2 + p3);
        pkv1[g2 * 2]     = pk2bf(p0, p1);
        pkv1[g2 * 2 + 1] = pk2bf(p2, p3);
      }
      union { unsigned u32[4]; bf16x8 v8; } A1, A2;
      A1.u32[0] = pkv1[0]; A1.u32[2] = pkv1[2];
      A1.u32[1] = pkv1[1]; A1.u32[3] = pkv1[3];
      A2.u32[0] = pkv1[4]; A2.u32[2] = pkv1[6];
      A2.u32[1] = pkv1[5]; A2.u32[3] = pkv1[7];
      if (!mir) {
        hswap_fwd(A1.u32[0], A1.u32[2]); hswap_fwd(A1.u32[1], A1.u32[3]);
        hswap_fwd(A2.u32[0], A2.u32[2]); hswap_fwd(A2.u32[1], A2.u32[3]);
      } else {
        hswap_rev(A1.u32[0], A1.u32[2]); hswap_rev(A1.u32[1], A1.u32[3]);
        hswap_rev(A2.u32[0], A2.u32[2]); hswap_rev(A2.u32[1], A2.u32[3]);
      }
      __builtin_amdgcn_s_setprio(1);
      o[0] = __builtin_amdgcn_mfma_f32_32x32x16_bf16(A1.v8, vb1[0][0], o[0], 0, 0, 0);
      o[1] = __builtin_amdgcn_mfma_f32_32x32x16_bf16(A1.v8, vb1[0][1], o[1], 0, 0, 0);
      o[0] = __builtin_amdgcn_mfma_f32_32x32x16_bf16(A2.v8, vb1[1][0], o[0], 0, 0, 0);
      o[1] = __builtin_amdgcn_mfma_f32_32x32x16_bf16(A2.v8, vb1[1][1], o[1], 0, 0, 0);
      __builtin_amdgcn_s_setprio(0);
    }
  }

  // lanes L and L+32 hold disjoint key subsets of the same q-row
  lsum += __shfl_xor(lsum, 32, 64);

  // ---- 2-phase merge: sum the 4 key-quarter waves ----
  const int prow = tid >> 4;          // 0..15 row within phase
  const int col4 = tid & 15;          // float4 column
  #pragma unroll
  for (int p = 0; p < 2; ++p) {
    const int rh = p;
    __syncthreads();
    #pragma unroll
    for (int r8 = 0; r8 < 8; ++r8) {
      const int r   = rh * 8 + r8;
      const int rip = (r8 & 3) + 4 * hl + 8 * (r8 >> 2);   // row in phase, 0..15
      oM[(wave * 16 + rip) * 72 + l32]      = o[0][r];
      oM[(wave * 16 + rip) * 72 + 32 + l32] = o[1][r];
    }
    if (lane < 32 && ((lane >> 4) & 1) == rh) lM[wave * 16 + (lane & 15)] = lsum;
    __syncthreads();
    float4 s = make_float4(0.f, 0.f, 0.f, 0.f);
    float l = 0.f;
    #pragma unroll
    for (int w = 0; w < 4; ++w) {
      float4 t4 = *(const float4*)&oM[(w * 16 + prow) * 72 + col4 * 4];
      s.x += t4.x; s.y += t4.y; s.z += t4.z; s.w += t4.w;
      l += lM[w * 16 + prow];
    }
    float inv = 1.f / l;
    const int grow = qc * 32 + p * 16 + prow;
    float4 st; st.x = s.x * inv; st.y = s.y * inv; st.z = s.z * inv; st.w = s.w * inv;
    *(float4*)(out + ((size_t)((n * SEQ + grow) * NH + h)) * DH + col4 * 4) = st;
  }
}

extern "C" void kernel_launch(void* const* d_in, const int* in_sizes, int n_in,
                              void* d_out, int out_size, void* d_ws, size_t ws_size,
                              hipStream_t stream) {
  const float* q = (const float*)d_in[0];
  const float* k = (const float*)d_in[1];
  const float* v = (const float*)d_in[2];
  float* out = (float*)d_out;
  (void)in_sizes; (void)n_in; (void)out_size; (void)ws_size;

  unsigned short* kb = (unsigned short*)d_ws;                       // 4 MB
  unsigned short* vb = kb + (size_t)HEADS * HSTRIDE;                // 4 MB

  pack_kv<<<HEADS * (SEQ / 64), 256, 0, stream>>>(k, v, kb, vb);
  attn<<<HEADS * (SEQ / 32), 256, 0, stream>>>(q, kb, vb, out);
}